// Round 6
// baseline (541.245 us; speedup 1.0000x reference)
//
#include <hip/hip_runtime.h>

#define N_NODES   50000
#define N_EDGES   800000
#define HIDDEN    100
#define NUM_TASKS 128
#define NUM_GRAPHS 2000
#define NBLK      7        // ceil(100/16) dim-blocks of 16
#define EPS 1e-16f

static __device__ __forceinline__ float rcp_fast(float v) {
    return __builtin_amdgcn_rcpf(v);  // 1-ulp v_rcp_f32
}
static __device__ __forceinline__ float invclip(float v) {
    // clip(v, EPS, 100) ** -1
    return rcp_fast(fminf(fmaxf(v, EPS), 100.0f));
}

// ---- init: deg=1 (self loop), cursor=0 ----
__global__ void init_kernel(int* __restrict__ deg, int* __restrict__ cursor) {
    int i = blockIdx.x * blockDim.x + threadIdx.x;
    if (i < N_NODES) { deg[i] = 1; cursor[i] = 0; }
}

// ---- in-degree (incl. self-loop via init=1) ----
__global__ void deg_count_kernel(const int* __restrict__ col, int* __restrict__ deg) {
    int e = blockIdx.x * blockDim.x + threadIdx.x;
    if (e < N_EDGES) atomicAdd(&deg[col[e]], 1);
}

// ---- hierarchical exclusive scan of (deg-1) -> csr_off ----
__global__ void blk_sum_kernel(const int* __restrict__ deg, int* __restrict__ bsum) {
    int i = blockIdx.x * 256 + threadIdx.x;
    int v = (i < N_NODES) ? (deg[i] - 1) : 0;
#pragma unroll
    for (int off = 32; off > 0; off >>= 1) v += __shfl_down(v, off, 64);
    __shared__ int ws[4];
    if ((threadIdx.x & 63) == 0) ws[threadIdx.x >> 6] = v;
    __syncthreads();
    if (threadIdx.x == 0) bsum[blockIdx.x] = ws[0] + ws[1] + ws[2] + ws[3];
}

__global__ void bsum_scan_kernel(int* __restrict__ bsum, int nblk) {
    __shared__ int buf[256];
    int t = threadIdx.x;
    int v = (t < nblk) ? bsum[t] : 0;
    buf[t] = v;
    __syncthreads();
    for (int off = 1; off < 256; off <<= 1) {
        int x = (t >= off) ? buf[t - off] : 0;
        __syncthreads();
        buf[t] += x;
        __syncthreads();
    }
    if (t < nblk) bsum[t] = buf[t] - v;  // exclusive base per block
}

// blk_scan + fused dinv
__global__ void blk_scan_kernel(const int* __restrict__ deg, const int* __restrict__ bbase,
                                int* __restrict__ csr_off, float* __restrict__ dinv) {
    __shared__ int buf[256];
    int t = threadIdx.x;
    int i = blockIdx.x * 256 + t;
    int dv = (i < N_NODES) ? deg[i] : 1;
    int v = (i < N_NODES) ? (dv - 1) : 0;
    buf[t] = v;
    __syncthreads();
    for (int off = 1; off < 256; off <<= 1) {
        int x = (t >= off) ? buf[t - off] : 0;
        __syncthreads();
        buf[t] += x;
        __syncthreads();
    }
    if (i < N_NODES) {
        csr_off[i] = bbase[blockIdx.x] + buf[t] - v;
        dinv[i] = 1.0f / sqrtf((float)dv);
    } else if (i == N_NODES) {
        csr_off[N_NODES] = N_EDGES;
    }
}

// ---- counting-sort edges by target; pack (src, norm) per slot ----
__global__ void scatter_kernel(const int* __restrict__ row, const int* __restrict__ col,
                               const int* __restrict__ csr_off, int* __restrict__ cursor,
                               const float* __restrict__ dinv, int2* __restrict__ csr_pack) {
    int e = blockIdx.x * blockDim.x + threadIdx.x;
    if (e >= N_EDGES) return;
    int s = row[e], d = col[e];
    int pos = csr_off[d] + atomicAdd(&cursor[d], 1);
    int2 p;
    p.x = s;
    p.y = __float_as_int(dinv[s] * dinv[d]);
    csr_pack[pos] = p;
}

// ---- AtomEncoder: h[n][d] = sum_f emb[x[n][f] + off[f]][d] (row-major out) ----
__global__ void encoder_kernel(const int* __restrict__ x, const float* __restrict__ emb,
                               float* __restrict__ h) {
    int n = blockIdx.x;
    int d = threadIdx.x;
    if (d >= HIDDEN) return;
    const int offs[9] = {0, 119, 124, 136, 148, 158, 164, 170, 172};
    float acc = 0.0f;
#pragma unroll
    for (int f = 0; f < 9; ++f) {
        int idx = x[n * 9 + f] + offs[f];
        acc += emb[idx * HIDDEN + d];
    }
    h[n * HIDDEN + d] = acc;
}

// ---- tiled matmul: 64-node tile; input row-major OR dim-blocked; output dim-blocked ----
// Blocked layout: buf[(b*N_NODES + n)*16 + d16] holds dim 16b+d16 of node n.
#define MM_NODES 64
#define HL_W     112   // padded row width (7 blocks * 16)
#define WL_PAD   10032
__global__ __launch_bounds__(512) void matmul_kernel(const float* __restrict__ in,
                                                     int in_blocked,
                                                     const float* __restrict__ W,
                                                     float* __restrict__ outb) {
    __shared__ float Wl[WL_PAD];
    __shared__ float hl[MM_NODES * HL_W];
    int tid = threadIdx.x;
    int nb = blockIdx.x * MM_NODES;

    for (int i = tid; i < WL_PAD; i += 512)
        Wl[i] = (i < HIDDEN * HIDDEN) ? W[i] : 0.0f;
    for (int i = tid; i < MM_NODES * HL_W; i += 512) {
        int n = i / HL_W, k = i % HL_W;
        int gn = nb + n;
        float v = 0.0f;
        if (gn < N_NODES && k < HIDDEN)
            v = in_blocked ? in[(((size_t)(k >> 4) * N_NODES + gn) << 4) + (k & 15)]
                           : in[(size_t)gn * HIDDEN + k];
        hl[i] = v;
    }
    __syncthreads();

    int tx = tid & 31;
    int ty = tid >> 5;  // 0..15

    float4 acc[4];
#pragma unroll
    for (int jn = 0; jn < 4; ++jn) acc[jn] = make_float4(0.f, 0.f, 0.f, 0.f);

    for (int kk = 0; kk < HIDDEN; kk += 4) {
        float hs[4][4];
#pragma unroll
        for (int jn = 0; jn < 4; ++jn) {
            float4 hv = *(const float4*)&hl[(ty + 16 * jn) * HL_W + kk];
            hs[jn][0] = hv.x; hs[jn][1] = hv.y; hs[jn][2] = hv.z; hs[jn][3] = hv.w;
        }
#pragma unroll
        for (int dk = 0; dk < 4; ++dk) {
            float4 wv = *(const float4*)&Wl[(kk + dk) * HIDDEN + 4 * tx];
#pragma unroll
            for (int jn = 0; jn < 4; ++jn) {
                acc[jn].x += hs[jn][dk] * wv.x;
                acc[jn].y += hs[jn][dk] * wv.y;
                acc[jn].z += hs[jn][dk] * wv.z;
                acc[jn].w += hs[jn][dk] * wv.w;
            }
        }
    }

    if (tx < 25) {  // dims 4tx..4tx+3 < 100
        int b = tx >> 2;
        int d16 = (4 * tx) & 15;
#pragma unroll
        for (int jn = 0; jn < 4; ++jn) {
            int n = nb + ty + 16 * jn;
            if (n < N_NODES)
                *(float4*)&outb[(((size_t)b * N_NODES + n) << 4) + d16] = acc[jn];
        }
    }
}

// ---- GCN aggregation, dim-blocked: wave = (node, dim-block) ----
// 64 lanes = 4 edge-groups x 16 dims. Per-pass gather footprint = 50k*64B =
// 3.2 MB -> fits each XCD's 4 MB L2 (grid ordered so all waves in flight share
// one dim-block). Shuffle-reduce partial sums across the 4 groups. Monotone
// early-exit: output saturates at 0.01 once total >= 100*cnt for all dims.
__global__ __launch_bounds__(256) void agg_kernel(
        const float* __restrict__ hwb, const int* __restrict__ csr_off,
        const int2* __restrict__ csr_pack, const float* __restrict__ dinv,
        const int* __restrict__ deg, const float* __restrict__ bias,
        float* __restrict__ outb, int relu) {
    int wid = (blockIdx.x * blockDim.x + threadIdx.x) >> 6;
    if (wid >= NBLK * N_NODES) return;
    int b = wid / N_NODES;          // consecutive waves share b -> L2 phase locality
    int n = wid - b * N_NODES;
    int lane = threadIdx.x & 63;
    int eg = lane >> 4, d16 = lane & 15;
    int d = (b << 4) + d16;
    bool valid = d < HIDDEN;

    float cnt = (float)deg[n];
    float thr = 100.0f * cnt;
    float dn  = dinv[n];
    float nrm = dn * dn;  // self-loop norm

    const float* blk = hwb + (((size_t)b * N_NODES) << 4);

    float acc;
    if (eg == 0) {
        if (valid) acc = invclip(nrm * blk[(n << 4) + d16]);
        else       acc = 3.0e38f;   // invalid dims never block the __all check
    } else {
        acc = 0.0f;
    }

    int beg = csr_off[n], end = csr_off[n + 1];
    for (int i = beg; i < end; i += 4) {
        int idx = i + eg;
        bool on = idx < end;
        int2 p = csr_pack[on ? idx : (end - 1)];
        float v = blk[(p.x << 4) + d16];
        if (on & valid) acc += invclip(__int_as_float(p.y) * v);
        if ((i - beg) & 4) {  // check every 2nd iteration (8 edges)
            float t = acc + __shfl_xor(acc, 16);
            t += __shfl_xor(t, 32);
            if (__all(t >= thr)) break;
        }
    }

    float tot = acc + __shfl_xor(acc, 16);
    tot += __shfl_xor(tot, 32);

    if (eg == 0 && valid) {
        float o = invclip(tot * rcp_fast(cnt)) + bias[d];
        if (relu) o = fmaxf(o, 0.f);
        outb[(((size_t)b * N_NODES + n) << 4) + d16] = o;
    }
}

// ---- fused mean-pool + linear head (blocked input; batch sorted) ----
__global__ void pool_final_kernel(const float* __restrict__ hb, const int* __restrict__ batch,
                                  const float* __restrict__ Wlin, const float* __restrict__ blin,
                                  float* __restrict__ out) {
    int g = blockIdx.x;
    int t = threadIdx.x;  // 128 = NUM_TASKS
    __shared__ float pl[HIDDEN];

    int lo = 0, hi = N_NODES;
    while (lo < hi) { int mid = (lo + hi) >> 1; if (batch[mid] < g) lo = mid + 1; else hi = mid; }
    int start = lo;
    hi = N_NODES;
    while (lo < hi) { int mid = (lo + hi) >> 1; if (batch[mid] < g + 1) lo = mid + 1; else hi = mid; }
    int end = lo;

    float inv = 1.0f / fmaxf((float)(end - start), 1.0f);
    if (t < HIDDEN) {
        const float* col = hb + (((size_t)(t >> 4) * N_NODES) << 4) + (t & 15);
        float acc = 0.f;
        for (int n = start; n < end; ++n) acc += col[(size_t)n << 4];
        pl[t] = acc * inv;
    }
    __syncthreads();

    float o = 0.f;
#pragma unroll 4
    for (int j = 0; j < HIDDEN; ++j) o += pl[j] * Wlin[j * NUM_TASKS + t];
    out[(size_t)g * NUM_TASKS + t] = o + blin[t];
}

extern "C" void kernel_launch(void* const* d_in, const int* in_sizes, int n_in,
                              void* d_out, int out_size, void* d_ws, size_t ws_size,
                              hipStream_t stream) {
    const int*   x     = (const int*)d_in[0];
    const int*   ei    = (const int*)d_in[1];
    const int*   batch = (const int*)d_in[2];
    const float* emb   = (const float*)d_in[3];
    const float* W1    = (const float*)d_in[4];
    const float* b1    = (const float*)d_in[5];
    const float* W2    = (const float*)d_in[6];
    const float* b2    = (const float*)d_in[7];
    const float* Wlin  = (const float*)d_in[8];
    const float* blin  = (const float*)d_in[9];
    float* out = (float*)d_out;

    const int* row = ei;             // edge_index[0] = source
    const int* col = ei + N_EDGES;   // edge_index[1] = target

    char* ws = (char*)d_ws;
    auto alloc = [&](size_t bytes) -> char* {
        char* p = ws;
        ws += (bytes + 255) & ~(size_t)255;
        return p;
    };
    const size_t BLK_ELEMS = (size_t)NBLK * N_NODES * 16;  // 5.6M floats = 22.4 MB
    int*   deg      = (int*)  alloc((size_t)N_NODES * 4);
    int*   cursor   = (int*)  alloc((size_t)N_NODES * 4);
    int*   csr_off  = (int*)  alloc((size_t)(N_NODES + 1) * 4);
    float* dinv     = (float*)alloc((size_t)N_NODES * 4);
    int2*  csr_pack = (int2*) alloc((size_t)N_EDGES * 8);
    float* bufR     = (float*)alloc(BLK_ELEMS * 4);  // enc out (row-major) / agg out (blocked)
    float* bufB     = (float*)alloc(BLK_ELEMS * 4);  // matmul out (blocked)
    int*   bsum     = (int*)  alloc(256 * 4);

    const int SCAN_BLOCKS = (N_NODES + 255) / 256;  // 196

    init_kernel<<<(N_NODES + 255) / 256, 256, 0, stream>>>(deg, cursor);
    deg_count_kernel<<<(N_EDGES + 255) / 256, 256, 0, stream>>>(col, deg);
    blk_sum_kernel<<<SCAN_BLOCKS, 256, 0, stream>>>(deg, bsum);
    bsum_scan_kernel<<<1, 256, 0, stream>>>(bsum, SCAN_BLOCKS);
    blk_scan_kernel<<<SCAN_BLOCKS, 256, 0, stream>>>(deg, bsum, csr_off, dinv);
    scatter_kernel<<<(N_EDGES + 255) / 256, 256, 0, stream>>>(row, col, csr_off, cursor, dinv,
                                                              csr_pack);
    encoder_kernel<<<N_NODES, 128, 0, stream>>>(x, emb, bufR);

    const int MM_BLOCKS  = (N_NODES + MM_NODES - 1) / MM_NODES;       // 782
    const int AGG_BLOCKS = (NBLK * N_NODES + 3) / 4;                  // 87500

    // conv1: hw = h0 @ W1 (row-in, blocked-out); agg -> relu -> h1 (blocked)
    matmul_kernel<<<MM_BLOCKS, 512, 0, stream>>>(bufR, 0, W1, bufB);
    agg_kernel<<<AGG_BLOCKS, 256, 0, stream>>>(bufB, csr_off, csr_pack,
                                               dinv, deg, b1, bufR, 1);
    // conv2 (blocked-in, blocked-out)
    matmul_kernel<<<MM_BLOCKS, 512, 0, stream>>>(bufR, 1, W2, bufB);
    agg_kernel<<<AGG_BLOCKS, 256, 0, stream>>>(bufB, csr_off, csr_pack,
                                               dinv, deg, b2, bufR, 0);

    pool_final_kernel<<<NUM_GRAPHS, 128, 0, stream>>>(bufR, batch, Wlin, blin, out);
}

// Round 7
// 305.425 us; speedup vs baseline: 1.7721x; 1.7721x over previous
//
#include <hip/hip_runtime.h>

#define N_NODES   50000
#define N_EDGES   800000
#define HIDDEN    100
#define NUM_TASKS 128
#define NUM_GRAPHS 2000
#define EPS 1e-16f

static __device__ __forceinline__ float rcp_fast(float v) {
    return __builtin_amdgcn_rcpf(v);  // 1-ulp v_rcp_f32
}
static __device__ __forceinline__ float invclip(float v) {
    // clip(v, EPS, 100) ** -1
    return rcp_fast(fminf(fmaxf(v, EPS), 100.0f));
}
static __device__ __forceinline__ unsigned pack_bf16x2(float a, float b) {
    unsigned r;
    asm("v_cvt_pk_bf16_f32 %0, %1, %2" : "=v"(r) : "v"(a), "v"(b));
    return r;  // low16 = bf16(a), high16 = bf16(b), RNE
}

// ---- init: deg=1 (self loop), cursor=0 ----
__global__ void init_kernel(int* __restrict__ deg, int* __restrict__ cursor) {
    int i = blockIdx.x * blockDim.x + threadIdx.x;
    if (i < N_NODES) { deg[i] = 1; cursor[i] = 0; }
}

// ---- in-degree (incl. self-loop via init=1) ----
__global__ void deg_count_kernel(const int* __restrict__ col, int* __restrict__ deg) {
    int e = blockIdx.x * blockDim.x + threadIdx.x;
    if (e < N_EDGES) atomicAdd(&deg[col[e]], 1);
}

// ---- hierarchical exclusive scan of (deg-1) -> csr_off ----
__global__ void blk_sum_kernel(const int* __restrict__ deg, int* __restrict__ bsum) {
    int i = blockIdx.x * 256 + threadIdx.x;
    int v = (i < N_NODES) ? (deg[i] - 1) : 0;
#pragma unroll
    for (int off = 32; off > 0; off >>= 1) v += __shfl_down(v, off, 64);
    __shared__ int ws[4];
    if ((threadIdx.x & 63) == 0) ws[threadIdx.x >> 6] = v;
    __syncthreads();
    if (threadIdx.x == 0) bsum[blockIdx.x] = ws[0] + ws[1] + ws[2] + ws[3];
}

__global__ void bsum_scan_kernel(int* __restrict__ bsum, int nblk) {
    __shared__ int buf[256];
    int t = threadIdx.x;
    int v = (t < nblk) ? bsum[t] : 0;
    buf[t] = v;
    __syncthreads();
    for (int off = 1; off < 256; off <<= 1) {
        int x = (t >= off) ? buf[t - off] : 0;
        __syncthreads();
        buf[t] += x;
        __syncthreads();
    }
    if (t < nblk) bsum[t] = buf[t] - v;  // exclusive base per block
}

// blk_scan + fused dinv
__global__ void blk_scan_kernel(const int* __restrict__ deg, const int* __restrict__ bbase,
                                int* __restrict__ csr_off, float* __restrict__ dinv) {
    __shared__ int buf[256];
    int t = threadIdx.x;
    int i = blockIdx.x * 256 + t;
    int dv = (i < N_NODES) ? deg[i] : 1;
    int v = (i < N_NODES) ? (dv - 1) : 0;
    buf[t] = v;
    __syncthreads();
    for (int off = 1; off < 256; off <<= 1) {
        int x = (t >= off) ? buf[t - off] : 0;
        __syncthreads();
        buf[t] += x;
        __syncthreads();
    }
    if (i < N_NODES) {
        csr_off[i] = bbase[blockIdx.x] + buf[t] - v;
        dinv[i] = 1.0f / sqrtf((float)dv);
    } else if (i == N_NODES) {
        csr_off[N_NODES] = N_EDGES;
    }
}

// ---- counting-sort edges by target; pack (src, norm) per slot ----
__global__ void scatter_kernel(const int* __restrict__ row, const int* __restrict__ col,
                               const int* __restrict__ csr_off, int* __restrict__ cursor,
                               const float* __restrict__ dinv, int2* __restrict__ csr_pack) {
    int e = blockIdx.x * blockDim.x + threadIdx.x;
    if (e >= N_EDGES) return;
    int s = row[e], d = col[e];
    int pos = csr_off[d] + atomicAdd(&cursor[d], 1);
    int2 p;
    p.x = s;
    p.y = __float_as_int(dinv[s] * dinv[d]);
    csr_pack[pos] = p;
}

// ---- AtomEncoder: h[n][d] = sum_f emb[x[n][f] + off[f]][d] ----
__global__ void encoder_kernel(const int* __restrict__ x, const float* __restrict__ emb,
                               float* __restrict__ h) {
    int n = blockIdx.x;
    int d = threadIdx.x;
    if (d >= HIDDEN) return;
    const int offs[9] = {0, 119, 124, 136, 148, 158, 164, 170, 172};
    float acc = 0.0f;
#pragma unroll
    for (int f = 0; f < 9; ++f) {
        int idx = x[n * 9 + f] + offs[f];
        acc += emb[idx * HIDDEN + d];
    }
    h[n * HIDDEN + d] = acc;
}

// ---- tiled matmul: 64-node tile, W + h-tile in LDS, 4x4 register tile ----
// Output: packed bf16x2, row-major [n][50] uints (uint k holds dims 2k,2k+1).
#define MM_NODES 64
#define WL_PAD   10032
__global__ __launch_bounds__(512) void matmul_kernel(const float* __restrict__ h,
                                                     const float* __restrict__ W,
                                                     unsigned* __restrict__ outb) {
    __shared__ float Wl[WL_PAD];
    __shared__ float hl[MM_NODES * HIDDEN];
    int tid = threadIdx.x;
    int nb = blockIdx.x * MM_NODES;

    for (int i = tid; i < WL_PAD; i += 512)
        Wl[i] = (i < HIDDEN * HIDDEN) ? W[i] : 0.0f;
    for (int i = tid; i < MM_NODES * HIDDEN; i += 512) {
        int n = i / HIDDEN;
        hl[i] = (nb + n < N_NODES) ? h[(size_t)(nb + n) * HIDDEN + (i % HIDDEN)] : 0.0f;
    }
    __syncthreads();

    int tx = tid & 31;
    int ty = tid >> 5;  // 0..15

    float4 acc[4];
#pragma unroll
    for (int jn = 0; jn < 4; ++jn) acc[jn] = make_float4(0.f, 0.f, 0.f, 0.f);

    for (int kk = 0; kk < HIDDEN; kk += 4) {
        float hs[4][4];
#pragma unroll
        for (int jn = 0; jn < 4; ++jn) {
            float4 hv = *(const float4*)&hl[(ty + 16 * jn) * HIDDEN + kk];
            hs[jn][0] = hv.x; hs[jn][1] = hv.y; hs[jn][2] = hv.z; hs[jn][3] = hv.w;
        }
#pragma unroll
        for (int dk = 0; dk < 4; ++dk) {
            float4 wv = *(const float4*)&Wl[(kk + dk) * HIDDEN + 4 * tx];
#pragma unroll
            for (int jn = 0; jn < 4; ++jn) {
                acc[jn].x += hs[jn][dk] * wv.x;
                acc[jn].y += hs[jn][dk] * wv.y;
                acc[jn].z += hs[jn][dk] * wv.z;
                acc[jn].w += hs[jn][dk] * wv.w;
            }
        }
    }

    if (tx < 25) {  // dims 4tx..4tx+3
#pragma unroll
        for (int jn = 0; jn < 4; ++jn) {
            int n = nb + ty + 16 * jn;
            if (n < N_NODES) {
                uint2 pk;
                pk.x = pack_bf16x2(acc[jn].x, acc[jn].y);
                pk.y = pack_bf16x2(acc[jn].z, acc[jn].w);
                *(uint2*)&outb[(size_t)n * 50 + 2 * tx] = pk;
            }
        }
    }
}

// ---- GCN aggregation: wave per node, bf16x2 gathers, unroll-4, early-exit ----
// Messages invclip(w*v) > 0 -> acc monotone; output saturates at exactly 0.01
// once acc >= 100*cnt for all lanes -> remaining edges provably irrelevant.
__global__ __launch_bounds__(256) void agg_kernel(
        const unsigned* __restrict__ hw16, const int* __restrict__ csr_off,
        const int2* __restrict__ csr_pack, const float* __restrict__ dinv,
        const int* __restrict__ deg, const float* __restrict__ bias,
        float* __restrict__ out, int relu) {
    int wid  = (blockIdx.x * blockDim.x + threadIdx.x) >> 6;
    int lane = threadIdx.x & 63;
    if (wid >= N_NODES) return;
    int n = wid;
    bool act = lane < 50;  // lane owns dims 2*lane (low16), 2*lane+1 (high16)

    float cnt = (float)deg[n];
    float thr = 100.0f * cnt;
    float dn  = dinv[n];
    float nrm = dn * dn;  // self-loop norm

    float2 acc;
    if (act) {
        unsigned u = hw16[(size_t)n * 50 + lane];
        acc.x = invclip(nrm * __int_as_float(u << 16));
        acc.y = invclip(nrm * __int_as_float(u & 0xFFFF0000u));
    } else {
        acc.x = 3.0e38f;  // inactive lanes never block the __all check
        acc.y = 3.0e38f;
    }

    int beg = csr_off[n], end = csr_off[n + 1];
    int i = beg;
    for (; i + 4 <= end; i += 4) {
        int2 p0 = csr_pack[i];
        int2 p1 = csr_pack[i + 1];
        int2 p2 = csr_pack[i + 2];
        int2 p3 = csr_pack[i + 3];
        unsigned u0 = act ? hw16[(size_t)p0.x * 50 + lane] : 0u;
        unsigned u1 = act ? hw16[(size_t)p1.x * 50 + lane] : 0u;
        unsigned u2 = act ? hw16[(size_t)p2.x * 50 + lane] : 0u;
        unsigned u3 = act ? hw16[(size_t)p3.x * 50 + lane] : 0u;
        float w0 = __int_as_float(p0.y), w1 = __int_as_float(p1.y);
        float w2 = __int_as_float(p2.y), w3 = __int_as_float(p3.y);
        acc.x += invclip(w0 * __int_as_float(u0 << 16));
        acc.y += invclip(w0 * __int_as_float(u0 & 0xFFFF0000u));
        acc.x += invclip(w1 * __int_as_float(u1 << 16));
        acc.y += invclip(w1 * __int_as_float(u1 & 0xFFFF0000u));
        acc.x += invclip(w2 * __int_as_float(u2 << 16));
        acc.y += invclip(w2 * __int_as_float(u2 & 0xFFFF0000u));
        acc.x += invclip(w3 * __int_as_float(u3 << 16));
        acc.y += invclip(w3 * __int_as_float(u3 & 0xFFFF0000u));
        if (__all((acc.x >= thr) & (acc.y >= thr))) { i = end; break; }
    }
    for (; i < end; ++i) {
        int2 p = csr_pack[i];
        unsigned u = act ? hw16[(size_t)p.x * 50 + lane] : 0u;
        float w = __int_as_float(p.y);
        acc.x += invclip(w * __int_as_float(u << 16));
        acc.y += invclip(w * __int_as_float(u & 0xFFFF0000u));
    }

    if (act) {
        float rcnt = rcp_fast(cnt);
        float2 o;
        o.x = invclip(acc.x * rcnt) + bias[2 * lane];
        o.y = invclip(acc.y * rcnt) + bias[2 * lane + 1];
        if (relu) { o.x = fmaxf(o.x, 0.f); o.y = fmaxf(o.y, 0.f); }
        *(float2*)&out[(size_t)n * HIDDEN + 2 * lane] = o;
    }
}

// ---- fused mean-pool + linear head (batch sorted -> binary search range) ----
__global__ void pool_final_kernel(const float* __restrict__ h, const int* __restrict__ batch,
                                  const float* __restrict__ Wlin, const float* __restrict__ blin,
                                  float* __restrict__ out) {
    int g = blockIdx.x;
    int t = threadIdx.x;  // 128 = NUM_TASKS
    __shared__ float pl[HIDDEN];

    int lo = 0, hi = N_NODES;
    while (lo < hi) { int mid = (lo + hi) >> 1; if (batch[mid] < g) lo = mid + 1; else hi = mid; }
    int start = lo;
    hi = N_NODES;
    while (lo < hi) { int mid = (lo + hi) >> 1; if (batch[mid] < g + 1) lo = mid + 1; else hi = mid; }
    int end = lo;

    float inv = 1.0f / fmaxf((float)(end - start), 1.0f);
    if (t < HIDDEN) {
        float acc = 0.f;
        for (int n = start; n < end; ++n) acc += h[(size_t)n * HIDDEN + t];
        pl[t] = acc * inv;
    }
    __syncthreads();

    float o = 0.f;
#pragma unroll 4
    for (int j = 0; j < HIDDEN; ++j) o += pl[j] * Wlin[j * NUM_TASKS + t];
    out[(size_t)g * NUM_TASKS + t] = o + blin[t];
}

extern "C" void kernel_launch(void* const* d_in, const int* in_sizes, int n_in,
                              void* d_out, int out_size, void* d_ws, size_t ws_size,
                              hipStream_t stream) {
    const int*   x     = (const int*)d_in[0];
    const int*   ei    = (const int*)d_in[1];
    const int*   batch = (const int*)d_in[2];
    const float* emb   = (const float*)d_in[3];
    const float* W1    = (const float*)d_in[4];
    const float* b1    = (const float*)d_in[5];
    const float* W2    = (const float*)d_in[6];
    const float* b2    = (const float*)d_in[7];
    const float* Wlin  = (const float*)d_in[8];
    const float* blin  = (const float*)d_in[9];
    float* out = (float*)d_out;

    const int* row = ei;             // edge_index[0] = source
    const int* col = ei + N_EDGES;   // edge_index[1] = target

    char* ws = (char*)d_ws;
    auto alloc = [&](size_t bytes) -> char* {
        char* p = ws;
        ws += (bytes + 255) & ~(size_t)255;
        return p;
    };
    int*      deg      = (int*)     alloc((size_t)N_NODES * 4);
    int*      cursor   = (int*)     alloc((size_t)N_NODES * 4);
    int*      csr_off  = (int*)     alloc((size_t)(N_NODES + 1) * 4);
    float*    dinv     = (float*)   alloc((size_t)N_NODES * 4);
    int2*     csr_pack = (int2*)    alloc((size_t)N_EDGES * 8);
    float*    bufA     = (float*)   alloc((size_t)N_NODES * HIDDEN * 4);  // h0/h1/h2
    unsigned* hw16     = (unsigned*)alloc((size_t)N_NODES * 50 * 4);      // packed bf16x2
    int*      bsum     = (int*)     alloc(256 * 4);

    const int SCAN_BLOCKS = (N_NODES + 255) / 256;  // 196

    init_kernel<<<(N_NODES + 255) / 256, 256, 0, stream>>>(deg, cursor);
    deg_count_kernel<<<(N_EDGES + 255) / 256, 256, 0, stream>>>(col, deg);
    blk_sum_kernel<<<SCAN_BLOCKS, 256, 0, stream>>>(deg, bsum);
    bsum_scan_kernel<<<1, 256, 0, stream>>>(bsum, SCAN_BLOCKS);
    blk_scan_kernel<<<SCAN_BLOCKS, 256, 0, stream>>>(deg, bsum, csr_off, dinv);
    scatter_kernel<<<(N_EDGES + 255) / 256, 256, 0, stream>>>(row, col, csr_off, cursor, dinv,
                                                              csr_pack);
    encoder_kernel<<<N_NODES, 128, 0, stream>>>(x, emb, bufA);

    const int MM_BLOCKS = (N_NODES + MM_NODES - 1) / MM_NODES;  // 782
    // conv1: hw = bf16(h0 @ W1); agg -> relu -> h1
    matmul_kernel<<<MM_BLOCKS, 512, 0, stream>>>(bufA, W1, hw16);
    agg_kernel<<<(N_NODES + 3) / 4, 256, 0, stream>>>(hw16, csr_off, csr_pack,
                                                      dinv, deg, b1, bufA, 1);
    // conv2
    matmul_kernel<<<MM_BLOCKS, 512, 0, stream>>>(bufA, W2, hw16);
    agg_kernel<<<(N_NODES + 3) / 4, 256, 0, stream>>>(hw16, csr_off, csr_pack,
                                                      dinv, deg, b2, bufA, 0);

    pool_final_kernel<<<NUM_GRAPHS, 128, 0, stream>>>(bufA, batch, Wlin, blin, out);
}